// Round 1
// baseline (634.403 us; speedup 1.0000x reference)
//
#include <hip/hip_runtime.h>
#include <math.h>

#define HW    2304      // 48*48
#define NPOS  442368    // 192*48*48

__device__ __forceinline__ float phi_f(float z) {
    return 0.5f * (1.0f + erff(z * 0.70710678118654752f));
}

// ---------------- Kernel A: repack masked W1 -> wt[tap*24+c], tap in [0,665) ----
__global__ __launch_bounds__(256) void prep_w1(const float* __restrict__ W1,
                                               float* __restrict__ wt) {
    int idx = blockIdx.x * 256 + threadIdx.x;
    if (idx < 665 * 24) {
        int tap = idx / 24, c = idx % 24;
        wt[idx] = W1[c * 1331 + tap];   // W1 is (24,1,11,11,11); mask keeps taps < 665
    }
}

// ---------------- Kernel B: conv2d hyper(384ch) -> h(192ch), 3x3, pad 1 --------
// grid (9 tiles, 48 oc-groups), 256 threads, each thread: 1 pixel x 4 ocs
#define ICS 8
__global__ __launch_bounds__(256) void conv2d_k(const float* __restrict__ hyper,
                                                const float* __restrict__ W3,
                                                const float* __restrict__ b3,
                                                float* __restrict__ hbuf) {
    __shared__ float sh[ICS][18][18];
    const int tile = blockIdx.x;          // 0..8
    const int oc0  = blockIdx.y * 4;      // 4 output channels per block
    const int tx0 = (tile % 3) * 16, ty0 = (tile / 3) * 16;
    const int tid = threadIdx.x;
    const int tx = tid & 15, ty = tid >> 4;

    float acc[4];
#pragma unroll
    for (int g = 0; g < 4; ++g) acc[g] = b3[oc0 + g];

    for (int ic0 = 0; ic0 < 384; ic0 += ICS) {
        __syncthreads();
        for (int i = tid; i < ICS * 324; i += 256) {
            int s = i / 324, r = i % 324, yy = r / 18, xx = r % 18;
            int gy = ty0 - 1 + yy, gx = tx0 - 1 + xx;
            float v = 0.f;
            if (gy >= 0 && gy < 48 && gx >= 0 && gx < 48)
                v = hyper[(ic0 + s) * HW + gy * 48 + gx];
            sh[s][yy][xx] = v;
        }
        __syncthreads();
        for (int s = 0; s < ICS; ++s) {
            const int ic = ic0 + s;
            const float* wp = W3 + (size_t)oc0 * 3456 + ic * 9;
#pragma unroll
            for (int kh = 0; kh < 3; ++kh)
#pragma unroll
                for (int kw = 0; kw < 3; ++kw) {
                    float xv = sh[s][ty + kh][tx + kw];
#pragma unroll
                    for (int g = 0; g < 4; ++g)
                        acc[g] = fmaf(wp[g * 3456 + kh * 3 + kw], xv, acc[g]);
                }
        }
    }
    const int py = ty0 + ty, px = tx0 + tx;
#pragma unroll
    for (int g = 0; g < 4; ++g)
        hbuf[(size_t)(oc0 + g) * HW + py * 48 + px] = acc[g];
}

// ---------------- Kernel C: fused conv3d + MLP + likelihood --------------------
// grid (9 tiles, 192 depths), 256 threads, 1 thread = 1 output position
__global__ __launch_bounds__(256) void fused_main(const float* __restrict__ x,
                                                  const float* __restrict__ wt,
                                                  const float* __restrict__ hbuf,
                                                  const float* __restrict__ b1,
                                                  const float* __restrict__ Wa,
                                                  const float* __restrict__ ba,
                                                  const float* __restrict__ Wb,
                                                  const float* __restrict__ bb,
                                                  const float* __restrict__ Wc,
                                                  const float* __restrict__ bc,
                                                  float* __restrict__ out) {
    __shared__ float sx[6][26][26];
    const int tile = blockIdx.x;      // 0..8
    const int d    = blockIdx.y;      // 0..191
    const int tx0 = (tile % 3) * 16, ty0 = (tile / 3) * 16;
    const int tid = threadIdx.x;
    const int tx = tid & 15, ty = tid >> 4;

    // stage 6 depth slices (d-5..d) with +-5 spatial halo, zero-padded
    for (int i = tid; i < 6 * 676; i += 256) {
        int zz = i / 676, r = i % 676, yy = r / 26, xx = r % 26;
        int gz = d - 5 + zz, gy = ty0 - 5 + yy, gx = tx0 - 5 + xx;
        float v = 0.f;
        if (gz >= 0 && gy >= 0 && gy < 48 && gx >= 0 && gx < 48)
            v = x[(size_t)gz * HW + gy * 48 + gx];
        sx[zz][yy][xx] = v;
    }
    __syncthreads();

    // ---- conv3d: 665 masked taps, 24 output channels ----
    float t0[25];
#pragma unroll
    for (int c = 0; c < 24; ++c) t0[c] = b1[c];

    for (int kd = 0; kd < 6; ++kd) {
        const int khmax = (kd < 5) ? 11 : 6;
        for (int kh = 0; kh < khmax; ++kh) {
            const int kwmax = (kd < 5 || kh < 5) ? 11 : 5;
            const float* wrow = wt + (kd * 121 + kh * 11) * 24;
            for (int kw = 0; kw < kwmax; ++kw) {
                float xv = sx[kd][ty + kh][tx + kw];
                const float* wp = wrow + kw * 24;
#pragma unroll
                for (int c = 0; c < 24; ++c)
                    t0[c] = fmaf(wp[c], xv, t0[c]);
            }
        }
    }

    const int pos = d * HW + (ty0 + ty) * 48 + (tx0 + tx);
    t0[24] = hbuf[pos];   // concat channel 24 = conv2d output

    // ---- layer a: 25 -> 48, relu ----
    float t1[48];
#pragma unroll
    for (int j = 0; j < 48; ++j) {
        float s = ba[j];
#pragma unroll
        for (int c = 0; c < 25; ++c) s = fmaf(Wa[j * 25 + c], t0[c], s);
        t1[j] = fmaxf(s, 0.f);
    }

    // ---- layers b (48->96, relu) and c (96->9) fused: never materialize t2 ----
    float o[9];
#pragma unroll
    for (int j = 0; j < 9; ++j) o[j] = bc[j];
    for (int c = 0; c < 96; ++c) {
        float s = bb[c];
#pragma unroll
        for (int k = 0; k < 48; ++k) s = fmaf(Wb[c * 48 + k], t1[k], s);
        s = fmaxf(s, 0.f);
#pragma unroll
        for (int j = 0; j < 9; ++j) o[j] = fmaf(Wc[j * 96 + c], s, o[j]);
    }

    // ---- likelihood ----
    float xv = x[pos];
    float m = fmaxf(o[6], fmaxf(o[7], o[8]));
    float e0 = expf(o[6] - m), e1 = expf(o[7] - m), e2 = expf(o[8] - m);
    float inv_es = 1.0f / (e0 + e1 + e2);
    float p = 0.f;
#pragma unroll
    for (int j = 0; j < 3; ++j) {
        float mu = o[j];
        float sc = o[3 + j];
        sc = (sc == 0.0f) ? 1e-9f : sc;
        sc = fabsf(sc);
        float a = phi_f((xv + 0.5f - mu) / sc);
        float b = phi_f((xv - 0.5f - mu) / sc);
        float lik = fabsf(a - b);
        float w = ((j == 0) ? e0 : (j == 1) ? e1 : e2) * inv_es;
        p = fmaf(w, lik, p);
    }

    // outputs: p3 (NPOS floats) then out (9*NPOS floats, channel-major)
    out[pos] = p;
    float* outc = out + NPOS;
#pragma unroll
    for (int j = 0; j < 9; ++j) outc[(size_t)j * NPOS + pos] = o[j];
}

extern "C" void kernel_launch(void* const* d_in, const int* in_sizes, int n_in,
                              void* d_out, int out_size, void* d_ws, size_t ws_size,
                              hipStream_t stream) {
    const float* x     = (const float*)d_in[0];
    const float* hyper = (const float*)d_in[1];
    const float* W3    = (const float*)d_in[2];
    const float* b3    = (const float*)d_in[3];
    const float* W1    = (const float*)d_in[4];
    const float* b1    = (const float*)d_in[5];
    const float* Wa    = (const float*)d_in[6];
    const float* ba    = (const float*)d_in[7];
    const float* Wb    = (const float*)d_in[8];
    const float* bb    = (const float*)d_in[9];
    const float* Wc    = (const float*)d_in[10];
    const float* bc    = (const float*)d_in[11];
    float* out = (float*)d_out;

    float* wt   = (float*)d_ws;          // 665*24 = 15960 floats
    float* hbuf = wt + 16384;            // 442368 floats

    prep_w1<<<63, 256, 0, stream>>>(W1, wt);
    conv2d_k<<<dim3(9, 48), 256, 0, stream>>>(hyper, W3, b3, hbuf);
    fused_main<<<dim3(9, 192), 256, 0, stream>>>(x, wt, hbuf, b1, Wa, ba, Wb, bb,
                                                 Wc, bc, out);
}